// Round 4
// baseline (634.999 us; speedup 1.0000x reference)
//
#include <hip/hip_runtime.h>

#define N_NODES 100000
#define N_EDGES 3200000
#define N_GRAPHS 1000
#define NLAYER 4
#define NB4 391          // coarse buckets: dst>>8, 391*256 = 100096 >= N_NODES
#define EPB4 4096        // edges per block in scatter pass
#define G1 782           // 782*4096 >= N_EDGES
#define PCAP3 10240      // bucket_sort perm capacity (mean 8192, sd ~90)

typedef __attribute__((ext_vector_type(8))) short bf16x8;
typedef __attribute__((ext_vector_type(4))) float f32x4;

// round-to-nearest-even f32 -> bf16 (finite inputs)
static __device__ __forceinline__ unsigned f2bf(float f) {
  unsigned u = __float_as_uint(f);
  return (u + 0x7fffu + ((u >> 16) & 1u)) >> 16;
}
static __device__ __forceinline__ float bf2f_lo(unsigned u) {
  return __uint_as_float(u << 16);
}
static __device__ __forceinline__ float bf2f_hi(unsigned u) {
  return __uint_as_float(u & 0xffff0000u);
}

// ---------------------------------------------------------------------------
// h_bf[v][c] = bf16(sum_k x[v][k]*emb_w[k][c] + emb_b[c]).
// Block 0 also zeroes tots (runs before hist1 in stream order).
__global__ __launch_bounds__(256) void embed_kernel(
    const float* __restrict__ x, const float* __restrict__ emb_w,
    const float* __restrict__ emb_b, unsigned short* __restrict__ h_bf,
    int* __restrict__ tots)
{
  if (blockIdx.x == 0) {
    for (int i = threadIdx.x; i < NB4; i += 256) tots[i] = 0;
  }
  int t = blockIdx.x * 256 + threadIdx.x;
  if (t >= N_NODES * 64) return;
  int c = t & 63, v = t >> 6;
  float4 xv = ((const float4*)x)[v];
  float acc = emb_b[c];
  acc = fmaf(xv.x, emb_w[0 * 64 + c], acc);
  acc = fmaf(xv.y, emb_w[1 * 64 + c], acc);
  acc = fmaf(xv.z, emb_w[2 * 64 + c], acc);
  acc = fmaf(xv.w, emb_w[3 * 64 + c], acc);
  h_bf[t] = (unsigned short)f2bf(acc);
}

// ---------------------------------------------------------------------------
// A: per-block LDS histogram of coarse bucket (dst>>8) -> global totals.
__global__ __launch_bounds__(256) void hist1_kernel(
    const int* __restrict__ ei, int* __restrict__ tots)
{
  __shared__ unsigned hist[NB4];
  for (int i = threadIdx.x; i < NB4; i += 256) hist[i] = 0;
  __syncthreads();
  int base = blockIdx.x * EPB4;
#pragma unroll
  for (int i = 0; i < 16; ++i) {
    int e = base + i * 256 + threadIdx.x;
    if (e < N_EDGES) atomicAdd(&hist[((unsigned)ei[N_EDGES + e]) >> 8], 1u);
  }
  __syncthreads();
  for (int i = threadIdx.x; i < NB4; i += 256) {
    unsigned c = hist[i];
    if (c) atomicAdd(&tots[i], (int)c);
  }
}

// B: exclusive scan of bucket totals -> bb[0..NB4]; init gcur = bb.
// Wave-shuffle scan, 3 barriers.
__global__ __launch_bounds__(1024) void scan1_kernel(
    const int* __restrict__ tots, int* __restrict__ bb, int* __restrict__ gcur)
{
  __shared__ int wsum[16];
  int t = threadIdx.x;
  int lane = t & 63;
  int w = t >> 6;
  int x = (t < NB4) ? tots[t] : 0;
  int s = x;
#pragma unroll
  for (int off = 1; off < 64; off <<= 1) {
    int y = __shfl_up(s, off);
    if (lane >= off) s += y;
  }
  if (lane == 63) wsum[w] = s;
  __syncthreads();
  if (w == 0 && lane < 16) {
    int v = wsum[lane];
    int ss = v;
#pragma unroll
    for (int off = 1; off < 16; off <<= 1) {
      int y = __shfl_up(ss, off);
      if (lane >= off) ss += y;
    }
    wsum[lane] = ss - v;  // exclusive wave offset
  }
  __syncthreads();
  int ex = wsum[w] + s - x;
  if (t < NB4) {
    bb[t] = ex;
    gcur[t] = ex;
  }
  if (t == 0) bb[NB4] = N_EDGES;
}

// C: staged scatter into coarse buckets. Histogram -> ONE global atomicAdd
// range-claim per (block,bucket) -> 3-barrier shuffle scan -> LDS stage in
// bucket order -> coalesced flush (84B avg runs). Record is the FINAL csr
// word (src|q15<<17, u32) + dst low byte (u8). Order within a bucket is
// arbitrary (only perturbs fp32 sum rounding).
__global__ __launch_bounds__(256) void bscatter4_kernel(
    const int* __restrict__ ei, const float* __restrict__ ea,
    int* __restrict__ gcur, unsigned* __restrict__ tmp_w,
    unsigned char* __restrict__ tmp_d)
{
  __shared__ unsigned hist[NB4];          // count -> local cursor
  __shared__ int dif[NB4];                // global_base - local_excl_base
  __shared__ unsigned stage_w[EPB4];      // 16 KB
  __shared__ unsigned char stage_d[EPB4]; // 4 KB
  __shared__ unsigned short bid[EPB4];    // 8 KB
  __shared__ int wpart[4];
  int tid = threadIdx.x;
  int base = blockIdx.x * EPB4;

  for (int i = tid; i < NB4; i += 256) hist[i] = 0;
  __syncthreads();

  int dreg[16];
#pragma unroll
  for (int i = 0; i < 16; ++i) {
    int e = base + i * 256 + tid;
    dreg[i] = -1;
    if (e < N_EDGES) {
      int d = ei[N_EDGES + e];
      dreg[i] = d;
      atomicAdd(&hist[((unsigned)d) >> 8], 1u);
    }
  }
  __syncthreads();

  // exclusive scan over NB4 buckets (2 per thread) + global range claim
  int lane = tid & 63, w = tid >> 6;
  int b0i = tid * 2, b1i = tid * 2 + 1;
  int c0 = (b0i < NB4) ? (int)hist[b0i] : 0;
  int c1 = (b1i < NB4) ? (int)hist[b1i] : 0;
  int tsum = c0 + c1;
  int s = tsum;
#pragma unroll
  for (int off = 1; off < 64; off <<= 1) {
    int y = __shfl_up(s, off);
    if (lane >= off) s += y;
  }
  if (lane == 63) wpart[w] = s;
  __syncthreads();
  int wo = 0;
  for (int ww = 0; ww < w; ++ww) wo += wpart[ww];
  int excl = wo + (s - tsum);  // exclusive prefix over thread sums
  if (b0i < NB4) {
    int gb = c0 ? atomicAdd(&gcur[b0i], c0) : 0;
    dif[b0i] = gb - excl;
    hist[b0i] = (unsigned)excl;  // local cursor
  }
  if (b1i < NB4) {
    int gb = c1 ? atomicAdd(&gcur[b1i], c1) : 0;
    dif[b1i] = gb - (excl + c0);
    hist[b1i] = (unsigned)(excl + c0);
  }
  __syncthreads();

  // stage in bucket-sorted order
#pragma unroll
  for (int i = 0; i < 16; ++i) {
    int e = base + i * 256 + tid;
    int d = dreg[i];
    if (d >= 0) {
      unsigned bkt = ((unsigned)d) >> 8;
      unsigned lp = atomicAdd(&hist[bkt], 1u);
      unsigned q15 = (unsigned)(ea[e] * 32768.0f);  // ew in [0,1)
      stage_w[lp] = ((unsigned)ei[e]) | (q15 << 17);
      stage_d[lp] = (unsigned char)(d & 255);
      bid[lp] = (unsigned short)bkt;
    }
  }
  __syncthreads();

  // coalesced flush
  int nE = min(EPB4, N_EDGES - base);
  for (int i = tid; i < nE; i += 256) {
    int g = dif[bid[i]] + i;
    tmp_w[g] = stage_w[i];
    tmp_d[g] = stage_d[i];
  }
}

// D: one block per bucket: 256-bin LDS counting sort (u16 permutation) ->
// contiguous streaming csr write; emits row_off and degw (from q15 weights).
__global__ __launch_bounds__(256) void bucket_sort3_kernel(
    const int* __restrict__ bb, const unsigned* __restrict__ tmp_w,
    const unsigned char* __restrict__ tmp_d,
    unsigned* __restrict__ csr, int* __restrict__ row_off, float* __restrict__ degw)
{
  int j = blockIdx.x;
  int b0 = bb[j], b1 = bb[j + 1];
  int nE = b1 - b0;
  __shared__ unsigned hist[256];
  __shared__ float dws[256];
  __shared__ unsigned cur[256];
  __shared__ int wpart[4];
  __shared__ unsigned short perm[PCAP3];  // 20 KB
  int t = threadIdx.x;
  hist[t] = 0;
  dws[t] = 0.f;
  __syncthreads();
  for (int i = t; i < nE; i += 256) {
    unsigned d = tmp_d[b0 + i];
    unsigned wrd = tmp_w[b0 + i];
    atomicAdd(&hist[d], 1u);
    atomicAdd(&dws[d], (float)(wrd >> 17) * (1.0f / 32768.0f));
  }
  __syncthreads();
  // shuffle exclusive scan of hist[256]
  int lane = t & 63, w = t >> 6;
  int v = (int)hist[t];
  int s = v;
#pragma unroll
  for (int off = 1; off < 64; off <<= 1) {
    int y = __shfl_up(s, off);
    if (lane >= off) s += y;
  }
  if (lane == 63) wpart[w] = s;
  __syncthreads();
  int wo = 0;
  for (int ww = 0; ww < w; ++ww) wo += wpart[ww];
  int excl = wo + s - v;
  cur[t] = (unsigned)excl;
  int vnode = (j << 8) + t;
  if (vnode < N_NODES) {
    row_off[vnode] = b0 + excl;
    degw[vnode] = dws[t];
  }
  if (j == NB4 - 1 && t == 0) row_off[N_NODES] = N_EDGES;
  __syncthreads();

  if (nE <= PCAP3) {
    for (int i = t; i < nE; i += 256) {
      unsigned p = atomicAdd(&cur[tmp_d[b0 + i]], 1u);
      perm[p] = (unsigned short)i;
    }
    __syncthreads();
    for (int q = t; q < nE; q += 256)
      csr[b0 + q] = tmp_w[b0 + (int)perm[q]];
  } else {
    for (int i = t; i < nE; i += 256) {
      unsigned p = atomicAdd(&cur[tmp_d[b0 + i]], 1u);
      csr[b0 + (int)p] = tmp_w[b0 + i];
    }
  }
}

// ---------------------------------------------------------------------------
// Degree-ordered node permutation (single block, 1024 threads): equalizes
// per-subgroup trip counts in agg. Replaces dhist/dscan/dperm.
__global__ __launch_bounds__(1024) void degsort_kernel(
    const int* __restrict__ row_off, int* __restrict__ nodeperm)
{
  __shared__ int h[256];
  __shared__ int wp[4];
  int t = threadIdx.x;
  if (t < 256) h[t] = 0;
  __syncthreads();
  for (int v = t; v < N_NODES; v += 1024) {
    int d = min(row_off[v + 1] - row_off[v], 255);
    atomicAdd(&h[d], 1);
  }
  __syncthreads();
  int lane = t & 63, w = t >> 6;
  int v0 = 0, s = 0;
  if (t < 256) {
    v0 = h[t];
    s = v0;
#pragma unroll
    for (int off = 1; off < 64; off <<= 1) {
      int y = __shfl_up(s, off);
      if (lane >= off) s += y;
    }
    if (lane == 63) wp[w] = s;
  }
  __syncthreads();
  if (t < 256) {
    int wo = 0;
    for (int ww = 0; ww < w; ++ww) wo += wp[ww];
    h[t] = wo + s - v0;  // exclusive base -> cursor
  }
  __syncthreads();
  for (int v = t; v < N_NODES; v += 1024) {
    int d = min(row_off[v + 1] - row_off[v], 255);
    int p = atomicAdd(&h[d], 1);
    nodeperm[p] = v;
  }
}

// ---------------------------------------------------------------------------
// One-time weight swizzle: all 4 layers' W2/W3/W1 into MFMA B-fragment
// layout in GLOBAL memory (4 x 24 KB). Verified mapping.
__global__ __launch_bounds__(256) void wswz_kernel(
    const float* __restrict__ cw1, const float* __restrict__ cw2,
    const float* __restrict__ cw3, unsigned* __restrict__ wswz)
{
  int l = blockIdx.x;
  const float* w1 = cw1 + l * 4096;
  const float* w2 = cw2 + l * 4096;
  const float* w3 = cw3 + l * 4096;
  unsigned* outp = wswz + l * 6144;
  int tid = threadIdx.x;
  int n = tid & 63;
  int gofs = tid >> 6;
  for (int it = 0; it < 24; ++it) {
    int g = it * 4 + gofs;         // 0..95
    int m = g >> 5;                // 0..2 (0=W2, 1=W3, 2=W1)
    int kp = g & 31;               // k-pair index
    int k = kp * 2;                // even k
    const float* W = (m == 0) ? w2 : (m == 1) ? w3 : w1;
    unsigned lo = f2bf(W[k * 64 + n]);
    unsigned hi = f2bf(W[(k + 1) * 64 + n]);
    int c = k >> 5;
    int kk = k & 31;
    int lane = ((kk >> 3) << 4) | (n & 15);
    int j2 = (kk & 7) >> 1;
    int t = n >> 4;
    outp[(((m * 2 + c) * 4 + t) << 8) | (lane << 2) | j2] = lo | (hi << 16);
  }
}

// ---------------------------------------------------------------------------
// MFMA matvec: one 16-node tile per wave.
//   a_bf  = bf16(h@W1 + b1)
//   cc_bf = bf16(b3 + h@W3 - deg_w*(h@W2))
__global__ __launch_bounds__(256) void matvec3_mfma_kernel(
    const unsigned short* __restrict__ h_bf,
    const unsigned* __restrict__ wz,   // this layer's 6144-word slice
    const float* __restrict__ b1, const float* __restrict__ b3,
    const float* __restrict__ degw,
    unsigned short* __restrict__ a_bf, unsigned short* __restrict__ cc_bf)
{
  int gw = (blockIdx.x * 256 + threadIdx.x) >> 6;  // global wave = tile index
  int lane = threadIdx.x & 63;
  int quad = lane >> 4;
  int col = lane & 15;
  int nb = gw * 16;  // node base of this wave's 16 rows
  if (nb >= N_NODES) return;  // wave-uniform exit

  int arow = nb + col;
  if (arow >= N_NODES) arow = N_NODES - 1;
  const bf16x8* ap = (const bf16x8*)(h_bf + (size_t)arow * 64 + quad * 8);
  bf16x8 af0 = ap[0];  // k = quad*8 + j
  bf16x8 af1 = ap[4];  // k = 32 + quad*8 + j

  float dwr[4];
#pragma unroll
  for (int r = 0; r < 4; ++r) {
    int row = nb + quad * 4 + r;
    dwr[r] = degw[row < N_NODES ? row : 0];
  }

#pragma unroll
  for (int t = 0; t < 4; ++t) {
    const bf16x8* b20 = (const bf16x8*)&wz[((0 * 4 + t) << 8) + lane * 4];
    const bf16x8* b21 = (const bf16x8*)&wz[((1 * 4 + t) << 8) + lane * 4];
    const bf16x8* b30 = (const bf16x8*)&wz[((2 * 4 + t) << 8) + lane * 4];
    const bf16x8* b31 = (const bf16x8*)&wz[((3 * 4 + t) << 8) + lane * 4];
    const bf16x8* b10 = (const bf16x8*)&wz[((4 * 4 + t) << 8) + lane * 4];
    const bf16x8* b11 = (const bf16x8*)&wz[((5 * 4 + t) << 8) + lane * 4];

    f32x4 z = {0.f, 0.f, 0.f, 0.f};
    f32x4 acc2 = __builtin_amdgcn_mfma_f32_16x16x32_bf16(af0, *b20, z, 0, 0, 0);
    acc2 = __builtin_amdgcn_mfma_f32_16x16x32_bf16(af1, *b21, acc2, 0, 0, 0);
    f32x4 cc;
#pragma unroll
    for (int r = 0; r < 4; ++r) cc[r] = -dwr[r] * acc2[r];
    cc = __builtin_amdgcn_mfma_f32_16x16x32_bf16(af0, *b30, cc, 0, 0, 0);
    cc = __builtin_amdgcn_mfma_f32_16x16x32_bf16(af1, *b31, cc, 0, 0, 0);
    float bb3 = b3[t * 16 + col];
#pragma unroll
    for (int r = 0; r < 4; ++r) {
      int row = nb + quad * 4 + r;
      if (row < N_NODES)
        cc_bf[(size_t)row * 64 + t * 16 + col] = (unsigned short)f2bf(cc[r] + bb3);
    }

    float bb1 = b1[t * 16 + col];
    f32x4 a1 = {bb1, bb1, bb1, bb1};
    a1 = __builtin_amdgcn_mfma_f32_16x16x32_bf16(af0, *b10, a1, 0, 0, 0);
    a1 = __builtin_amdgcn_mfma_f32_16x16x32_bf16(af1, *b11, a1, 0, 0, 0);
#pragma unroll
    for (int r = 0; r < 4; ++r) {
      int row = nb + quad * 4 + r;
      if (row < N_NODES)
        a_bf[(size_t)row * 64 + t * 16 + col] = (unsigned short)f2bf(a1[r]);
    }
  }
}

// ---------------------------------------------------------------------------
// h_new[v] = relu(cc[v] + sum_{e in CSR(v)} ew_e * a[src_e])
// 4 nodes/wave (degree-sorted via nodeperm), 16 lanes per node; exact
// per-subgroup trip counts. a/cc bf16; csr u32 (src|q15<<17).
__global__ __launch_bounds__(256) void agg_kernel(
    const uint2* __restrict__ a2, const uint2* __restrict__ cc2,
    const int* __restrict__ row_off, const unsigned* __restrict__ csr,
    const int* __restrict__ nodeperm,
    float4* __restrict__ h4, unsigned short* __restrict__ h_bf, int write_h)
{
  int wave = (blockIdx.x * 256 + threadIdx.x) >> 6;
  int lane = threadIdx.x & 63;
  int sg = lane >> 4;
  int li = lane & 15;
  int lsel = (lane & 48) << 2;  // sg*64 : byte lane-address base for bpermute
  int vslot = wave * 4 + sg;
  bool valid = vslot < N_NODES;
  int v = nodeperm[valid ? vslot : N_NODES - 1];
  int base = row_off[v];
  int ecnt = valid ? (row_off[v + 1] - base) : 0;

  float4 acc = make_float4(0.f, 0.f, 0.f, 0.f);
  if (valid) {
    uint2 cu = cc2[(size_t)v * 16 + li];
    acc.x = bf2f_lo(cu.x);
    acc.y = bf2f_hi(cu.x);
    acc.z = bf2f_lo(cu.y);
    acc.w = bf2f_hi(cu.y);
  }
  const uint2* ap = a2 + li;

  int full = ecnt & ~15;
  int c0 = 0;
  for (; c0 < full; c0 += 16) {
    int er = (int)csr[base + c0 + li];  // always in-row: c0+15 < ecnt
#pragma unroll
    for (int j = 0; j < 16; ++j) {
      unsigned r = (unsigned)__builtin_amdgcn_ds_bpermute(lsel | (j << 2), er);
      int s = (int)(r & 0x1FFFFu);
      float w = (float)(r >> 17) * (1.0f / 32768.0f);
      uint2 u = ap[(size_t)s * 16];
      acc.x = fmaf(w, bf2f_lo(u.x), acc.x);
      acc.y = fmaf(w, bf2f_hi(u.x), acc.y);
      acc.z = fmaf(w, bf2f_lo(u.y), acc.z);
      acc.w = fmaf(w, bf2f_hi(u.y), acc.w);
    }
  }
  int rem = ecnt - full;
  if (rem > 0) {
    int idx = c0 + li;
    int er = (idx < ecnt) ? (int)csr[base + idx] : 0;
    for (int j = 0; j < rem; ++j) {
      unsigned r = (unsigned)__builtin_amdgcn_ds_bpermute(lsel | (j << 2), er);
      int s = (int)(r & 0x1FFFFu);
      float w = (float)(r >> 17) * (1.0f / 32768.0f);
      uint2 u = ap[(size_t)s * 16];
      acc.x = fmaf(w, bf2f_lo(u.x), acc.x);
      acc.y = fmaf(w, bf2f_hi(u.x), acc.y);
      acc.z = fmaf(w, bf2f_lo(u.y), acc.z);
      acc.w = fmaf(w, bf2f_hi(u.y), acc.w);
    }
  }
  if (valid) {
    acc.x = fmaxf(acc.x, 0.f);
    acc.y = fmaxf(acc.y, 0.f);
    acc.z = fmaxf(acc.z, 0.f);
    acc.w = fmaxf(acc.w, 0.f);
    if (write_h) h4[(size_t)v * 16 + li] = acc;
    uint2 p;
    p.x = f2bf(acc.x) | (f2bf(acc.y) << 16);
    p.y = f2bf(acc.z) | (f2bf(acc.w) << 16);
    ((uint2*)h_bf)[(size_t)v * 16 + li] = p;
  }
}

// ---------------------------------------------------------------------------
// fused mean-pool (sorted batch, binary search) + lin1+relu + lin2, wave/graph
__global__ __launch_bounds__(256) void head_kernel(
    const float* __restrict__ h, const int* __restrict__ batch,
    const float* __restrict__ l1w, const float* __restrict__ l1b,
    const float* __restrict__ l2w, const float* __restrict__ l2b,
    float* __restrict__ out)
{
  int g = (blockIdx.x * 256 + threadIdx.x) >> 6;
  int lane = threadIdx.x & 63;
  if (g >= N_GRAPHS) return;
  int lo = 0, hi = N_NODES;
  while (lo < hi) { int mid = (lo + hi) >> 1; if (batch[mid] < g) lo = mid + 1; else hi = mid; }
  int start = lo;
  hi = N_NODES;
  while (lo < hi) { int mid = (lo + hi) >> 1; if (batch[mid] < g + 1) lo = mid + 1; else hi = mid; }
  int end = lo;

  float sum = 0.f;
  for (int v = start; v < end; ++v) sum += h[(size_t)v * 64 + lane];
  float cntf = (float)(end - start);
  float gx = sum / fmaxf(cntf, 1.f);

  float acc = l1b[lane];
  for (int k = 0; k < 64; ++k) {
    float gxk = __shfl(gx, k);
    acc = fmaf(gxk, l1w[k * 64 + lane], acc);
  }
  float t = fmaxf(acc, 0.f);
  float p0 = t * l2w[lane * 3 + 0];
  float p1 = t * l2w[lane * 3 + 1];
  float p2 = t * l2w[lane * 3 + 2];
  for (int off = 32; off > 0; off >>= 1) {
    p0 += __shfl_down(p0, off);
    p1 += __shfl_down(p1, off);
    p2 += __shfl_down(p2, off);
  }
  if (lane == 0) {
    out[g * 3 + 0] = p0 + l2b[0];
    out[g * 3 + 1] = p1 + l2b[1];
    out[g * 3 + 2] = p2 + l2b[2];
  }
}

// ---------------------------------------------------------------------------
extern "C" void kernel_launch(void* const* d_in, const int* in_sizes, int n_in,
                              void* d_out, int out_size, void* d_ws, size_t ws_size,
                              hipStream_t stream)
{
  (void)in_sizes; (void)n_in; (void)out_size; (void)ws_size;
  const float* x     = (const float*)d_in[0];
  const int*   ei    = (const int*)d_in[1];
  const float* ea    = (const float*)d_in[2];
  const int*   batch = (const int*)d_in[3];
  const float* emb_w = (const float*)d_in[4];
  const float* emb_b = (const float*)d_in[5];
  const float* cw1   = (const float*)d_in[6];
  const float* cb1   = (const float*)d_in[7];
  const float* cw2   = (const float*)d_in[8];
  const float* cw3   = (const float*)d_in[9];
  const float* cb3   = (const float*)d_in[10];
  const float* l1w   = (const float*)d_in[11];
  const float* l1b   = (const float*)d_in[12];
  const float* l2w   = (const float*)d_in[13];
  const float* l2b   = (const float*)d_in[14];
  float* out = (float*)d_out;

  char* wsb = (char*)d_ws;
  size_t off = 0;
  auto alloc = [&](size_t bytes) {
    char* p = wsb + off;
    off = (off + bytes + 255) & ~(size_t)255;
    return p;
  };
  float* h       = (float*)alloc(sizeof(float) * (size_t)N_NODES * 64);    // 25.6 MB
  unsigned short* h_bf = (unsigned short*)alloc(sizeof(short) * (size_t)N_NODES * 64);
  unsigned short* a_bf = (unsigned short*)alloc(sizeof(short) * (size_t)N_NODES * 64);
  unsigned short* cc_bf = (unsigned short*)alloc(sizeof(short) * (size_t)N_NODES * 64);
  unsigned* csr  = (unsigned*)alloc(sizeof(unsigned) * (size_t)N_EDGES);   // 12.8 MB
  int*   row_off = (int*)alloc(sizeof(int) * (N_NODES + 1));
  float* degw    = (float*)alloc(sizeof(float) * N_NODES);
  int*   nodeperm= (int*)alloc(sizeof(int) * N_NODES);
  int*   tots    = (int*)alloc(sizeof(int) * NB4);
  int*   bb      = (int*)alloc(sizeof(int) * (NB4 + 1));
  int*   gcur    = (int*)alloc(sizeof(int) * NB4);
  unsigned* wswz = (unsigned*)alloc(sizeof(unsigned) * NLAYER * 6144);  // 96 KB
  // tmp_w (12.8 MB) + tmp_d (3.2 MB) alias h: h fp32 is only written by the
  // LAST agg, long after bucket_sort consumed tmp.
  unsigned* tmp_w = (unsigned*)h;
  unsigned char* tmp_d = (unsigned char*)h + sizeof(unsigned) * (size_t)N_EDGES;

  embed_kernel<<<(N_NODES * 64 + 255) / 256, 256, 0, stream>>>(
      x, emb_w, emb_b, h_bf, tots);
  wswz_kernel<<<NLAYER, 256, 0, stream>>>(cw1, cw2, cw3, wswz);
  hist1_kernel<<<G1, 256, 0, stream>>>(ei, tots);
  scan1_kernel<<<1, 1024, 0, stream>>>(tots, bb, gcur);
  bscatter4_kernel<<<G1, 256, 0, stream>>>(ei, ea, gcur, tmp_w, tmp_d);
  bucket_sort3_kernel<<<NB4, 256, 0, stream>>>(bb, tmp_w, tmp_d, csr, row_off, degw);
  degsort_kernel<<<1, 1024, 0, stream>>>(row_off, nodeperm);

  int agg_blocks = (N_NODES + 15) / 16;   // 4 nodes/wave, 4 waves/block
  int mv_blocks = (N_NODES / 16 + 3) / 4 + 1;
  for (int l = 0; l < NLAYER; ++l) {
    matvec3_mfma_kernel<<<mv_blocks, 256, 0, stream>>>(
        h_bf, wswz + l * 6144, cb1 + l * 64, cb3 + l * 64, degw, a_bf, cc_bf);
    agg_kernel<<<agg_blocks, 256, 0, stream>>>(
        (const uint2*)a_bf, (const uint2*)cc_bf, row_off, csr, nodeperm, (float4*)h,
        h_bf, (l == NLAYER - 1) ? 1 : 0);
  }

  head_kernel<<<(N_GRAPHS * 64 + 255) / 256, 256, 0, stream>>>(
      h, batch, l1w, l1b, l2w, l2b, out);
}

// Round 6
// 552.969 us; speedup vs baseline: 1.1483x; 1.1483x over previous
//
#include <hip/hip_runtime.h>

#define N_NODES 100000
#define N_EDGES 3200000
#define N_GRAPHS 1000
#define NLAYER 4
#define NB4 391          // coarse buckets: dst>>8, 391*256 = 100096 >= N_NODES
#define EPB4 4096        // edges per block in scatter pass
#define G1 782           // 782*4096 >= N_EDGES
#define PCAP3 10240      // bucket_sort perm capacity (mean 8192, sd ~90)

typedef __attribute__((ext_vector_type(8))) short bf16x8;
typedef __attribute__((ext_vector_type(4))) float f32x4;

// round-to-nearest-even f32 -> bf16 (finite inputs)
static __device__ __forceinline__ unsigned f2bf(float f) {
  unsigned u = __float_as_uint(f);
  return (u + 0x7fffu + ((u >> 16) & 1u)) >> 16;
}
static __device__ __forceinline__ float bf2f_lo(unsigned u) {
  return __uint_as_float(u << 16);
}
static __device__ __forceinline__ float bf2f_hi(unsigned u) {
  return __uint_as_float(u & 0xffff0000u);
}

// ---------------------------------------------------------------------------
// h_bf[v][c] = bf16(sum_k x[v][k]*emb_w[k][c] + emb_b[c]).
// Block 0 also zeroes tots (separate kernel boundary before hist1).
__global__ __launch_bounds__(256) void embed_kernel(
    const float* __restrict__ x, const float* __restrict__ emb_w,
    const float* __restrict__ emb_b, unsigned short* __restrict__ h_bf,
    int* __restrict__ tots)
{
  if (blockIdx.x == 0) {
    for (int i = threadIdx.x; i < NB4; i += 256) tots[i] = 0;
  }
  int t = blockIdx.x * 256 + threadIdx.x;
  if (t >= N_NODES * 64) return;
  int c = t & 63, v = t >> 6;
  float4 xv = ((const float4*)x)[v];
  float acc = emb_b[c];
  acc = fmaf(xv.x, emb_w[0 * 64 + c], acc);
  acc = fmaf(xv.y, emb_w[1 * 64 + c], acc);
  acc = fmaf(xv.z, emb_w[2 * 64 + c], acc);
  acc = fmaf(xv.w, emb_w[3 * 64 + c], acc);
  h_bf[t] = (unsigned short)f2bf(acc);
}

// ---------------------------------------------------------------------------
// A: per-block LDS histogram of coarse bucket (dst>>8) -> global totals.
__global__ __launch_bounds__(256) void hist1_kernel(
    const int* __restrict__ ei, int* __restrict__ tots)
{
  __shared__ unsigned hist[NB4];
  for (int i = threadIdx.x; i < NB4; i += 256) hist[i] = 0;
  __syncthreads();
  int base = blockIdx.x * EPB4;
#pragma unroll
  for (int i = 0; i < 16; ++i) {
    int e = base + i * 256 + threadIdx.x;
    if (e < N_EDGES) atomicAdd(&hist[((unsigned)ei[N_EDGES + e]) >> 8], 1u);
  }
  __syncthreads();
  for (int i = threadIdx.x; i < NB4; i += 256) {
    unsigned c = hist[i];
    if (c) atomicAdd(&tots[i], (int)c);
  }
}

// B: exclusive scan of bucket totals -> bb[0..NB4]; init gcur = bb.
// Wave-shuffle scan, 3 barriers.
__global__ __launch_bounds__(1024) void scan1_kernel(
    const int* __restrict__ tots, int* __restrict__ bb, int* __restrict__ gcur)
{
  __shared__ int wsum[16];
  int t = threadIdx.x;
  int lane = t & 63;
  int w = t >> 6;
  int x = (t < NB4) ? tots[t] : 0;
  int s = x;
#pragma unroll
  for (int off = 1; off < 64; off <<= 1) {
    int y = __shfl_up(s, off);
    if (lane >= off) s += y;
  }
  if (lane == 63) wsum[w] = s;
  __syncthreads();
  if (w == 0 && lane < 16) {
    int v = wsum[lane];
    int ss = v;
#pragma unroll
    for (int off = 1; off < 16; off <<= 1) {
      int y = __shfl_up(ss, off);
      if (lane >= off) ss += y;
    }
    wsum[lane] = ss - v;  // exclusive wave offset
  }
  __syncthreads();
  int ex = wsum[w] + s - x;
  if (t < NB4) {
    bb[t] = ex;
    gcur[t] = ex;
  }
  if (t == 0) bb[NB4] = N_EDGES;
}

// C: staged scatter into coarse buckets. Histogram -> ONE global atomicAdd
// range-claim per (block,bucket) -> 3-barrier shuffle scan -> LDS stage in
// bucket order -> coalesced flush (84B avg runs). Record is the FINAL csr
// word (src|q15<<17, u32) + dst low byte (u8). Order within a bucket is
// arbitrary (only perturbs fp32 sum rounding).
__global__ __launch_bounds__(256) void bscatter4_kernel(
    const int* __restrict__ ei, const float* __restrict__ ea,
    int* __restrict__ gcur, unsigned* __restrict__ tmp_w,
    unsigned char* __restrict__ tmp_d)
{
  __shared__ unsigned hist[NB4];          // count -> local cursor
  __shared__ int dif[NB4];                // global_base - local_excl_base
  __shared__ unsigned stage_w[EPB4];      // 16 KB
  __shared__ unsigned char stage_d[EPB4]; // 4 KB
  __shared__ unsigned short bid[EPB4];    // 8 KB
  __shared__ int wpart[4];
  int tid = threadIdx.x;
  int base = blockIdx.x * EPB4;

  for (int i = tid; i < NB4; i += 256) hist[i] = 0;
  __syncthreads();

  int dreg[16];
#pragma unroll
  for (int i = 0; i < 16; ++i) {
    int e = base + i * 256 + tid;
    dreg[i] = -1;
    if (e < N_EDGES) {
      int d = ei[N_EDGES + e];
      dreg[i] = d;
      atomicAdd(&hist[((unsigned)d) >> 8], 1u);
    }
  }
  __syncthreads();

  // exclusive scan over NB4 buckets (2 per thread) + global range claim
  int lane = tid & 63, w = tid >> 6;
  int b0i = tid * 2, b1i = tid * 2 + 1;
  int c0 = (b0i < NB4) ? (int)hist[b0i] : 0;
  int c1 = (b1i < NB4) ? (int)hist[b1i] : 0;
  int tsum = c0 + c1;
  int s = tsum;
#pragma unroll
  for (int off = 1; off < 64; off <<= 1) {
    int y = __shfl_up(s, off);
    if (lane >= off) s += y;
  }
  if (lane == 63) wpart[w] = s;
  __syncthreads();
  int wo = 0;
  for (int ww = 0; ww < w; ++ww) wo += wpart[ww];
  int excl = wo + (s - tsum);  // exclusive prefix over thread sums
  if (b0i < NB4) {
    int gb = c0 ? atomicAdd(&gcur[b0i], c0) : 0;
    dif[b0i] = gb - excl;
    hist[b0i] = (unsigned)excl;  // local cursor
  }
  if (b1i < NB4) {
    int gb = c1 ? atomicAdd(&gcur[b1i], c1) : 0;
    dif[b1i] = gb - (excl + c0);
    hist[b1i] = (unsigned)(excl + c0);
  }
  __syncthreads();

  // stage in bucket-sorted order
#pragma unroll
  for (int i = 0; i < 16; ++i) {
    int e = base + i * 256 + tid;
    int d = dreg[i];
    if (d >= 0) {
      unsigned bkt = ((unsigned)d) >> 8;
      unsigned lp = atomicAdd(&hist[bkt], 1u);
      unsigned q15 = (unsigned)(ea[e] * 32768.0f);  // ew in [0,1)
      stage_w[lp] = ((unsigned)ei[e]) | (q15 << 17);
      stage_d[lp] = (unsigned char)(d & 255);
      bid[lp] = (unsigned short)bkt;
    }
  }
  __syncthreads();

  // coalesced flush
  int nE = min(EPB4, N_EDGES - base);
  for (int i = tid; i < nE; i += 256) {
    int g = dif[bid[i]] + i;
    tmp_w[g] = stage_w[i];
    tmp_d[g] = stage_d[i];
  }
}

// D: one block per bucket: 256-bin LDS counting sort (u16 permutation) ->
// contiguous streaming csr write; emits row_off and degw (from q15 weights).
__global__ __launch_bounds__(256) void bucket_sort3_kernel(
    const int* __restrict__ bb, const unsigned* __restrict__ tmp_w,
    const unsigned char* __restrict__ tmp_d,
    unsigned* __restrict__ csr, int* __restrict__ row_off, float* __restrict__ degw)
{
  int j = blockIdx.x;
  int b0 = bb[j], b1 = bb[j + 1];
  int nE = b1 - b0;
  __shared__ unsigned hist[256];
  __shared__ float dws[256];
  __shared__ unsigned cur[256];
  __shared__ int wpart[4];
  __shared__ unsigned short perm[PCAP3];  // 20 KB
  int t = threadIdx.x;
  hist[t] = 0;
  dws[t] = 0.f;
  __syncthreads();
  for (int i = t; i < nE; i += 256) {
    unsigned d = tmp_d[b0 + i];
    unsigned wrd = tmp_w[b0 + i];
    atomicAdd(&hist[d], 1u);
    atomicAdd(&dws[d], (float)(wrd >> 17) * (1.0f / 32768.0f));
  }
  __syncthreads();
  // shuffle exclusive scan of hist[256]
  int lane = t & 63, w = t >> 6;
  int v = (int)hist[t];
  int s = v;
#pragma unroll
  for (int off = 1; off < 64; off <<= 1) {
    int y = __shfl_up(s, off);
    if (lane >= off) s += y;
  }
  if (lane == 63) wpart[w] = s;
  __syncthreads();
  int wo = 0;
  for (int ww = 0; ww < w; ++ww) wo += wpart[ww];
  int excl = wo + s - v;
  cur[t] = (unsigned)excl;
  int vnode = (j << 8) + t;
  if (vnode < N_NODES) {
    row_off[vnode] = b0 + excl;
    degw[vnode] = dws[t];
  }
  if (j == NB4 - 1 && t == 0) row_off[N_NODES] = N_EDGES;
  __syncthreads();

  if (nE <= PCAP3) {
    for (int i = t; i < nE; i += 256) {
      unsigned p = atomicAdd(&cur[tmp_d[b0 + i]], 1u);
      perm[p] = (unsigned short)i;
    }
    __syncthreads();
    for (int q = t; q < nE; q += 256)
      csr[b0 + q] = tmp_w[b0 + (int)perm[q]];
  } else {
    for (int i = t; i < nE; i += 256) {
      unsigned p = atomicAdd(&cur[tmp_d[b0 + i]], 1u);
      csr[b0 + (int)p] = tmp_w[b0 + i];
    }
  }
}

// ---------------------------------------------------------------------------
// One-time weight swizzle: all 4 layers' W2/W3/W1 into MFMA B-fragment
// layout in GLOBAL memory (4 x 24 KB). Verified mapping.
__global__ __launch_bounds__(256) void wswz_kernel(
    const float* __restrict__ cw1, const float* __restrict__ cw2,
    const float* __restrict__ cw3, unsigned* __restrict__ wswz)
{
  int l = blockIdx.x;
  const float* w1 = cw1 + l * 4096;
  const float* w2 = cw2 + l * 4096;
  const float* w3 = cw3 + l * 4096;
  unsigned* outp = wswz + l * 6144;
  int tid = threadIdx.x;
  int n = tid & 63;
  int gofs = tid >> 6;
  for (int it = 0; it < 24; ++it) {
    int g = it * 4 + gofs;         // 0..95
    int m = g >> 5;                // 0..2 (0=W2, 1=W3, 2=W1)
    int kp = g & 31;               // k-pair index
    int k = kp * 2;                // even k
    const float* W = (m == 0) ? w2 : (m == 1) ? w3 : w1;
    unsigned lo = f2bf(W[k * 64 + n]);
    unsigned hi = f2bf(W[(k + 1) * 64 + n]);
    int c = k >> 5;
    int kk = k & 31;
    int lane = ((kk >> 3) << 4) | (n & 15);
    int j2 = (kk & 7) >> 1;
    int t = n >> 4;
    outp[(((m * 2 + c) * 4 + t) << 8) | (lane << 2) | j2] = lo | (hi << 16);
  }
}

// ---------------------------------------------------------------------------
// MFMA matvec: one 16-node tile per wave.
//   a_bf  = bf16(h@W1 + b1)
//   cc_bf = bf16(b3 + h@W3 - deg_w*(h@W2))
__global__ __launch_bounds__(256) void matvec3_mfma_kernel(
    const unsigned short* __restrict__ h_bf,
    const unsigned* __restrict__ wz,   // this layer's 6144-word slice
    const float* __restrict__ b1, const float* __restrict__ b3,
    const float* __restrict__ degw,
    unsigned short* __restrict__ a_bf, unsigned short* __restrict__ cc_bf)
{
  int gw = (blockIdx.x * 256 + threadIdx.x) >> 6;  // global wave = tile index
  int lane = threadIdx.x & 63;
  int quad = lane >> 4;
  int col = lane & 15;
  int nb = gw * 16;  // node base of this wave's 16 rows
  if (nb >= N_NODES) return;  // wave-uniform exit

  int arow = nb + col;
  if (arow >= N_NODES) arow = N_NODES - 1;
  const bf16x8* ap = (const bf16x8*)(h_bf + (size_t)arow * 64 + quad * 8);
  bf16x8 af0 = ap[0];  // k = quad*8 + j
  bf16x8 af1 = ap[4];  // k = 32 + quad*8 + j

  float dwr[4];
#pragma unroll
  for (int r = 0; r < 4; ++r) {
    int row = nb + quad * 4 + r;
    dwr[r] = degw[row < N_NODES ? row : 0];
  }

#pragma unroll
  for (int t = 0; t < 4; ++t) {
    const bf16x8* b20 = (const bf16x8*)&wz[((0 * 4 + t) << 8) + lane * 4];
    const bf16x8* b21 = (const bf16x8*)&wz[((1 * 4 + t) << 8) + lane * 4];
    const bf16x8* b30 = (const bf16x8*)&wz[((2 * 4 + t) << 8) + lane * 4];
    const bf16x8* b31 = (const bf16x8*)&wz[((3 * 4 + t) << 8) + lane * 4];
    const bf16x8* b10 = (const bf16x8*)&wz[((4 * 4 + t) << 8) + lane * 4];
    const bf16x8* b11 = (const bf16x8*)&wz[((5 * 4 + t) << 8) + lane * 4];

    f32x4 z = {0.f, 0.f, 0.f, 0.f};
    f32x4 acc2 = __builtin_amdgcn_mfma_f32_16x16x32_bf16(af0, *b20, z, 0, 0, 0);
    acc2 = __builtin_amdgcn_mfma_f32_16x16x32_bf16(af1, *b21, acc2, 0, 0, 0);
    f32x4 cc;
#pragma unroll
    for (int r = 0; r < 4; ++r) cc[r] = -dwr[r] * acc2[r];
    cc = __builtin_amdgcn_mfma_f32_16x16x32_bf16(af0, *b30, cc, 0, 0, 0);
    cc = __builtin_amdgcn_mfma_f32_16x16x32_bf16(af1, *b31, cc, 0, 0, 0);
    float bb3 = b3[t * 16 + col];
#pragma unroll
    for (int r = 0; r < 4; ++r) {
      int row = nb + quad * 4 + r;
      if (row < N_NODES)
        cc_bf[(size_t)row * 64 + t * 16 + col] = (unsigned short)f2bf(cc[r] + bb3);
    }

    float bb1 = b1[t * 16 + col];
    f32x4 a1 = {bb1, bb1, bb1, bb1};
    a1 = __builtin_amdgcn_mfma_f32_16x16x32_bf16(af0, *b10, a1, 0, 0, 0);
    a1 = __builtin_amdgcn_mfma_f32_16x16x32_bf16(af1, *b11, a1, 0, 0, 0);
#pragma unroll
    for (int r = 0; r < 4; ++r) {
      int row = nb + quad * 4 + r;
      if (row < N_NODES)
        a_bf[(size_t)row * 64 + t * 16 + col] = (unsigned short)f2bf(a1[r]);
    }
  }
}

// ---------------------------------------------------------------------------
// h_new[v] = relu(cc[v] + sum_{e in CSR(v)} ew_e * a[src_e])
// 4 consecutive nodes/wave, 16 lanes per node; wave-max trip count (keeps
// csr/cc/h accesses contiguous across the wave's 4 nodes). a/cc bf16;
// csr u32 (src 17b | q15 15b).
__global__ __launch_bounds__(256) void agg_kernel(
    const uint2* __restrict__ a2, const uint2* __restrict__ cc2,
    const int* __restrict__ row_off, const unsigned* __restrict__ csr,
    float4* __restrict__ h4, unsigned short* __restrict__ h_bf, int write_h)
{
  int wave = (blockIdx.x * 256 + threadIdx.x) >> 6;
  int lane = threadIdx.x & 63;
  int sg = lane >> 4;
  int li = lane & 15;
  int lsel = (lane & 48) << 2;  // sg*64 : byte lane-address base for bpermute
  int v = wave * 4 + sg;
  bool valid = v < N_NODES;
  int vc = valid ? v : N_NODES - 1;
  int base = row_off[vc];
  int ecnt = valid ? (row_off[vc + 1] - base) : 0;
  int emax = ecnt;
  emax = max(emax, __shfl_xor(emax, 16));
  emax = max(emax, __shfl_xor(emax, 32));

  float4 acc = make_float4(0.f, 0.f, 0.f, 0.f);
  if (valid) {
    uint2 cu = cc2[(size_t)vc * 16 + li];
    acc.x = bf2f_lo(cu.x);
    acc.y = bf2f_hi(cu.x);
    acc.z = bf2f_lo(cu.y);
    acc.w = bf2f_hi(cu.y);
  }
  const uint2* ap = a2 + li;

  int full = emax & ~15;
  int c0 = 0;
  for (; c0 < full; c0 += 16) {
    int idx = c0 + li;
    int er = (idx < ecnt) ? (int)csr[base + idx] : 0;  // pad: src 0, w 0
#pragma unroll
    for (int j = 0; j < 16; ++j) {
      unsigned r = (unsigned)__builtin_amdgcn_ds_bpermute(lsel | (j << 2), er);
      int s = (int)(r & 0x1FFFFu);
      float w = (float)(r >> 17) * (1.0f / 32768.0f);
      uint2 u = ap[(size_t)s * 16];
      acc.x = fmaf(w, bf2f_lo(u.x), acc.x);
      acc.y = fmaf(w, bf2f_hi(u.x), acc.y);
      acc.z = fmaf(w, bf2f_lo(u.y), acc.z);
      acc.w = fmaf(w, bf2f_hi(u.y), acc.w);
    }
  }
  int rem = emax - full;
  if (rem > 0) {
    int idx = c0 + li;
    int er = (idx < ecnt) ? (int)csr[base + idx] : 0;
    for (int j = 0; j < rem; ++j) {
      unsigned r = (unsigned)__builtin_amdgcn_ds_bpermute(lsel | (j << 2), er);
      int s = (int)(r & 0x1FFFFu);
      float w = (float)(r >> 17) * (1.0f / 32768.0f);
      uint2 u = ap[(size_t)s * 16];
      acc.x = fmaf(w, bf2f_lo(u.x), acc.x);
      acc.y = fmaf(w, bf2f_hi(u.x), acc.y);
      acc.z = fmaf(w, bf2f_lo(u.y), acc.z);
      acc.w = fmaf(w, bf2f_hi(u.y), acc.w);
    }
  }
  if (valid) {
    acc.x = fmaxf(acc.x, 0.f);
    acc.y = fmaxf(acc.y, 0.f);
    acc.z = fmaxf(acc.z, 0.f);
    acc.w = fmaxf(acc.w, 0.f);
    if (write_h) h4[(size_t)v * 16 + li] = acc;
    uint2 p;
    p.x = f2bf(acc.x) | (f2bf(acc.y) << 16);
    p.y = f2bf(acc.z) | (f2bf(acc.w) << 16);
    ((uint2*)h_bf)[(size_t)v * 16 + li] = p;
  }
}

// ---------------------------------------------------------------------------
// fused mean-pool (sorted batch, binary search) + lin1+relu + lin2, wave/graph
__global__ __launch_bounds__(256) void head_kernel(
    const float* __restrict__ h, const int* __restrict__ batch,
    const float* __restrict__ l1w, const float* __restrict__ l1b,
    const float* __restrict__ l2w, const float* __restrict__ l2b,
    float* __restrict__ out)
{
  int g = (blockIdx.x * 256 + threadIdx.x) >> 6;
  int lane = threadIdx.x & 63;
  if (g >= N_GRAPHS) return;
  int lo = 0, hi = N_NODES;
  while (lo < hi) { int mid = (lo + hi) >> 1; if (batch[mid] < g) lo = mid + 1; else hi = mid; }
  int start = lo;
  hi = N_NODES;
  while (lo < hi) { int mid = (lo + hi) >> 1; if (batch[mid] < g + 1) lo = mid + 1; else hi = mid; }
  int end = lo;

  float sum = 0.f;
  for (int v = start; v < end; ++v) sum += h[(size_t)v * 64 + lane];
  float cntf = (float)(end - start);
  float gx = sum / fmaxf(cntf, 1.f);

  float acc = l1b[lane];
  for (int k = 0; k < 64; ++k) {
    float gxk = __shfl(gx, k);
    acc = fmaf(gxk, l1w[k * 64 + lane], acc);
  }
  float t = fmaxf(acc, 0.f);
  float p0 = t * l2w[lane * 3 + 0];
  float p1 = t * l2w[lane * 3 + 1];
  float p2 = t * l2w[lane * 3 + 2];
  for (int off = 32; off > 0; off >>= 1) {
    p0 += __shfl_down(p0, off);
    p1 += __shfl_down(p1, off);
    p2 += __shfl_down(p2, off);
  }
  if (lane == 0) {
    out[g * 3 + 0] = p0 + l2b[0];
    out[g * 3 + 1] = p1 + l2b[1];
    out[g * 3 + 2] = p2 + l2b[2];
  }
}

// ---------------------------------------------------------------------------
extern "C" void kernel_launch(void* const* d_in, const int* in_sizes, int n_in,
                              void* d_out, int out_size, void* d_ws, size_t ws_size,
                              hipStream_t stream)
{
  (void)in_sizes; (void)n_in; (void)out_size; (void)ws_size;
  const float* x     = (const float*)d_in[0];
  const int*   ei    = (const int*)d_in[1];
  const float* ea    = (const float*)d_in[2];
  const int*   batch = (const int*)d_in[3];
  const float* emb_w = (const float*)d_in[4];
  const float* emb_b = (const float*)d_in[5];
  const float* cw1   = (const float*)d_in[6];
  const float* cb1   = (const float*)d_in[7];
  const float* cw2   = (const float*)d_in[8];
  const float* cw3   = (const float*)d_in[9];
  const float* cb3   = (const float*)d_in[10];
  const float* l1w   = (const float*)d_in[11];
  const float* l1b   = (const float*)d_in[12];
  const float* l2w   = (const float*)d_in[13];
  const float* l2b   = (const float*)d_in[14];
  float* out = (float*)d_out;

  char* wsb = (char*)d_ws;
  size_t off = 0;
  auto alloc = [&](size_t bytes) {
    char* p = wsb + off;
    off = (off + bytes + 255) & ~(size_t)255;
    return p;
  };
  float* h       = (float*)alloc(sizeof(float) * (size_t)N_NODES * 64);    // 25.6 MB
  unsigned short* h_bf = (unsigned short*)alloc(sizeof(short) * (size_t)N_NODES * 64);
  unsigned short* a_bf = (unsigned short*)alloc(sizeof(short) * (size_t)N_NODES * 64);
  unsigned short* cc_bf = (unsigned short*)alloc(sizeof(short) * (size_t)N_NODES * 64);
  unsigned* csr  = (unsigned*)alloc(sizeof(unsigned) * (size_t)N_EDGES);   // 12.8 MB
  int*   row_off = (int*)alloc(sizeof(int) * (N_NODES + 1));
  float* degw    = (float*)alloc(sizeof(float) * N_NODES);
  int*   tots    = (int*)alloc(sizeof(int) * NB4);
  int*   bb      = (int*)alloc(sizeof(int) * (NB4 + 1));
  int*   gcur    = (int*)alloc(sizeof(int) * NB4);
  unsigned* wswz = (unsigned*)alloc(sizeof(unsigned) * NLAYER * 6144);  // 96 KB
  // tmp_w (12.8 MB) + tmp_d (3.2 MB) alias h: h fp32 is only written by the
  // LAST agg, long after bucket_sort consumed tmp.
  unsigned* tmp_w = (unsigned*)h;
  unsigned char* tmp_d = (unsigned char*)h + sizeof(unsigned) * (size_t)N_EDGES;

  embed_kernel<<<(N_NODES * 64 + 255) / 256, 256, 0, stream>>>(
      x, emb_w, emb_b, h_bf, tots);
  wswz_kernel<<<NLAYER, 256, 0, stream>>>(cw1, cw2, cw3, wswz);
  hist1_kernel<<<G1, 256, 0, stream>>>(ei, tots);
  scan1_kernel<<<1, 1024, 0, stream>>>(tots, bb, gcur);
  bscatter4_kernel<<<G1, 256, 0, stream>>>(ei, ea, gcur, tmp_w, tmp_d);
  bucket_sort3_kernel<<<NB4, 256, 0, stream>>>(bb, tmp_w, tmp_d, csr, row_off, degw);

  int agg_blocks = (N_NODES + 15) / 16;   // 4 nodes/wave, 4 waves/block
  int mv_blocks = (N_NODES / 16 + 3) / 4 + 1;
  for (int l = 0; l < NLAYER; ++l) {
    matvec3_mfma_kernel<<<mv_blocks, 256, 0, stream>>>(
        h_bf, wswz + l * 6144, cb1 + l * 64, cb3 + l * 64, degw, a_bf, cc_bf);
    agg_kernel<<<agg_blocks, 256, 0, stream>>>(
        (const uint2*)a_bf, (const uint2*)cc_bf, row_off, csr, (float4*)h,
        h_bf, (l == NLAYER - 1) ? 1 : 0);
  }

  head_kernel<<<(N_GRAPHS * 64 + 255) / 256, 256, 0, stream>>>(
      h, batch, l1w, l1b, l2w, l2b, out);
}